// Round 2
// 926.006 us; speedup vs baseline: 1.8135x; 1.8135x over previous
//
#include <hip/hip_runtime.h>
#include <hip/hip_bf16.h>

#define B_ 2
#define N_ 8
#define C_ 64
#define H_ 192
#define W_ 256
#define V_ 200000
#define OUT_ 128
#define HW_ (H_*W_)        // 49152
#define R_ (N_*HW_)        // 393216
#define BV_ (B_*V_)        // 400000
#define BR_ (B_*R_)        // 786432
#define SCAN_E 2048
#define SCAN_BLOCKS ((BV_ + SCAN_E - 1)/SCAN_E)   // 196

// ---------------- Kernel 1: ray directions ----------------
__global__ __launch_bounds__(256) void ray_kernel(
    const float* __restrict__ pose,
    const float* __restrict__ intr,
    float* __restrict__ dout)
{
    const int blocksPerBN = HW_ / 256;  // 192
    int tid = threadIdx.x;
    int bn = blockIdx.x / blocksPerBN;
    int hw = (blockIdx.x % blocksPerBN) * 256 + tid;
    int h = hw / W_, w = hw % W_;

    __shared__ float p[12];
    __shared__ float it[4];
    if (tid < 12) p[tid] = pose[bn * 16 + tid];
    if (tid >= 12 && tid < 16) it[tid - 12] = intr[bn * 6 + (tid - 12)];
    __syncthreads();

    float fx = it[0], fy = it[1], cx = it[2], cy = it[3];
    float uu = ((float)w - cx) / fx;
    float vv = ((float)h - cy) / fy;
    float dx = p[0] * uu + p[1] * vv + p[2];
    float dy = p[4] * uu + p[5] * vv + p[6];
    float dz = p[8] * uu + p[9] * vv + p[10];
    float inv = rsqrtf(dx * dx + dy * dy + dz * dz);
    size_t o = (size_t)(bn * HW_ + hw) * 3;
    dout[o + 0] = dx * inv;
    dout[o + 1] = dy * inv;
    dout[o + 2] = dz * inv;
}

// ---------------- Sort path: histogram ----------------
__global__ __launch_bounds__(256) void hist_kernel(
    const int* __restrict__ vox,
    const int* __restrict__ hit,
    unsigned* __restrict__ hist)
{
    int t = blockIdx.x * 256 + threadIdx.x;   // 0 .. BR_-1
    if (t >= BR_) return;
    int b = t / R_;
    if (hit[t]) atomicAdd(&hist[b * V_ + vox[t]], 1u);
}

// ---------------- Sort path: 3-phase exclusive scan over hist[BV_] ----------------
__global__ __launch_bounds__(256) void scanA_kernel(
    const unsigned* __restrict__ hist,
    unsigned* __restrict__ blockSums)
{
    int tid = threadIdx.x;
    int base = blockIdx.x * SCAN_E + tid * 8;
    unsigned s = 0;
    #pragma unroll
    for (int j = 0; j < 8; ++j) {
        int idx = base + j;
        if (idx < BV_) s += hist[idx];
    }
    __shared__ unsigned sh[256];
    sh[tid] = s; __syncthreads();
    for (int d = 128; d > 0; d >>= 1) {
        if (tid < d) sh[tid] += sh[tid + d];
        __syncthreads();
    }
    if (tid == 0) blockSums[blockIdx.x] = sh[0];
}

__global__ __launch_bounds__(256) void scanB_kernel(
    const unsigned* __restrict__ blockSums,
    unsigned* __restrict__ blockOffsets)
{
    int tid = threadIdx.x;
    unsigned v = (tid < SCAN_BLOCKS) ? blockSums[tid] : 0u;
    __shared__ unsigned sh[256];
    sh[tid] = v; __syncthreads();
    for (int d = 1; d < 256; d <<= 1) {
        unsigned t = (tid >= d) ? sh[tid - d] : 0u;
        __syncthreads();
        sh[tid] += t;
        __syncthreads();
    }
    if (tid < SCAN_BLOCKS) blockOffsets[tid] = sh[tid] - v;   // exclusive
}

__global__ __launch_bounds__(256) void scanC_kernel(
    const unsigned* __restrict__ hist,
    const unsigned* __restrict__ blockOffsets,
    unsigned* __restrict__ offsets)
{
    int tid = threadIdx.x;
    int base = blockIdx.x * SCAN_E + tid * 8;
    unsigned e[8];
    unsigned s = 0;
    #pragma unroll
    for (int j = 0; j < 8; ++j) {
        int idx = base + j;
        e[j] = (idx < BV_) ? hist[idx] : 0u;
        s += e[j];
    }
    __shared__ unsigned sh[256];
    sh[tid] = s; __syncthreads();
    for (int d = 1; d < 256; d <<= 1) {
        unsigned t = (tid >= d) ? sh[tid - d] : 0u;
        __syncthreads();
        sh[tid] += t;
        __syncthreads();
    }
    unsigned run = blockOffsets[blockIdx.x] + (sh[tid] - s);
    #pragma unroll
    for (int j = 0; j < 8; ++j) {
        int idx = base + j;
        if (idx < BV_) offsets[idx] = run;
        run += e[j];
    }
}

// ---------------- Sort path: ticket permute (indices only) ----------------
// After this kernel, offsets[key] == segment_end (= original offset + hist[key]).
__global__ __launch_bounds__(256) void permute_kernel(
    const int* __restrict__ vox,
    const int* __restrict__ hit,
    unsigned* __restrict__ offsets,
    unsigned* __restrict__ sortedIdx)
{
    int t = blockIdx.x * 256 + threadIdx.x;
    if (t >= BR_) return;
    int b = t / R_;
    int r = t - b * R_;
    if (!hit[t]) return;
    int key = b * V_ + vox[t];
    unsigned pos = atomicAdd(&offsets[key], 1u);
    sortedIdx[pos] = (unsigned)r;
}

// ---------------- Sort path: segmented gather-mean ----------------
// One wave per (b,v); lanes = channels. No float atomics.
__global__ __launch_bounds__(256) void gather_kernel(
    const float* __restrict__ feat,
    const unsigned* __restrict__ hist,
    const unsigned* __restrict__ offsets,
    const unsigned* __restrict__ sortedIdx,
    float* __restrict__ means)
{
    int lane = threadIdx.x & 63;
    int wid = (blockIdx.x * 256 + threadIdx.x) >> 6;   // 0 .. BV_-1
    if (wid >= BV_) return;
    int b = wid / V_;
    unsigned cnt = hist[wid];
    unsigned end = offsets[wid];          // segment end after permute
    unsigned start = end - cnt;
    const float* fb = feat + (size_t)b * N_ * C_ * HW_ + (size_t)lane * HW_;
    float acc = 0.0f;
    for (unsigned k = 0; k < cnt; ++k) {
        unsigned r = sortedIdx[start + k];
        unsigned n = r / HW_;
        unsigned hw = r - n * HW_;
        acc += fb[(size_t)n * (C_ * HW_) + hw];
    }
    means[(size_t)wid * C_ + lane] = acc / fmaxf((float)cnt, 1.0f);
}

// ---------------- Sort path: concat(conf) + GEMM + bias (means precomputed) ----------------
__global__ __launch_bounds__(256) void gemm_mean_kernel(
    const float* __restrict__ means,
    const float* __restrict__ conf,
    const float* __restrict__ wfc,
    const float* __restrict__ bfc,
    float* __restrict__ outp)
{
    const int VPB = 32;
    __shared__ float wl[65][128];
    __shared__ float voxT[65][36];
    __shared__ float bl[128];
    int tid = threadIdx.x;
    int bv0 = blockIdx.x * VPB;

    for (int i = tid; i < 65 * 128; i += 256)
        wl[i >> 7][i & 127] = wfc[i];
    if (tid < 128) bl[tid] = bfc[tid];
    if (tid < VPB) voxT[64][tid] = conf[bv0 + tid];
    for (int i = tid; i < VPB * C_; i += 256) {
        int vx = i >> 6, c = i & 63;
        voxT[c][vx] = means[(size_t)bv0 * C_ + i];
    }
    __syncthreads();

    int oc = tid & 31;
    int vr = tid >> 5;
    float acc[4][4];
    float4 bq = *(float4*)&bl[oc * 4];
    #pragma unroll
    for (int i = 0; i < 4; ++i) {
        acc[i][0] = bq.x; acc[i][1] = bq.y; acc[i][2] = bq.z; acc[i][3] = bq.w;
    }

    #pragma unroll
    for (int c = 0; c < 65; ++c) {
        float4 v4 = *(float4*)&voxT[c][vr * 4];
        float4 w4 = *(float4*)&wl[c][oc * 4];
        acc[0][0] += v4.x * w4.x; acc[0][1] += v4.x * w4.y; acc[0][2] += v4.x * w4.z; acc[0][3] += v4.x * w4.w;
        acc[1][0] += v4.y * w4.x; acc[1][1] += v4.y * w4.y; acc[1][2] += v4.y * w4.z; acc[1][3] += v4.y * w4.w;
        acc[2][0] += v4.z * w4.x; acc[2][1] += v4.z * w4.y; acc[2][2] += v4.z * w4.z; acc[2][3] += v4.z * w4.w;
        acc[3][0] += v4.w * w4.x; acc[3][1] += v4.w * w4.y; acc[3][2] += v4.w * w4.z; acc[3][3] += v4.w * w4.w;
    }

    #pragma unroll
    for (int i = 0; i < 4; ++i) {
        size_t bv = (size_t)(bv0 + vr * 4 + i);
        float4 st;
        st.x = acc[i][0]; st.y = acc[i][1]; st.z = acc[i][2]; st.w = acc[i][3];
        *(float4*)&outp[bv * OUT_ + oc * 4] = st;
    }
}

// ---------------- Fallback atomic path (previous verified kernels) ----------------
__global__ __launch_bounds__(256) void scatter_kernel(
    const float* __restrict__ feat,
    const int* __restrict__ vox_ids,
    const int* __restrict__ hit,
    float* __restrict__ sums,
    unsigned* __restrict__ cnts)
{
    const int PPT = 2;
    const int blocksPerBN = HW_ / (256 * PPT);  // 96
    int tid = threadIdx.x;
    int bn = blockIdx.x / blocksPerBN;
    int b = bn >> 3;
    int hw0 = (blockIdx.x % blocksPerBN) * (256 * PPT) + tid * PPT;
    int r0 = (bn & 7) * HW_ + hw0;

    int2 vid = *(const int2*)(vox_ids + (size_t)b * R_ + r0);
    int2 ht  = *(const int2*)(hit + (size_t)b * R_ + r0);
    if (!(ht.x | ht.y)) return;

    unsigned* cb = cnts + (size_t)b * V_;
    if (ht.x) atomicAdd(&cb[vid.x], 1u);
    if (ht.y) atomicAdd(&cb[vid.y], 1u);

    float* sb = sums + (size_t)b * (size_t)V_ * C_;
    float* s0 = sb + (size_t)vid.x * C_;
    float* s1 = sb + (size_t)vid.y * C_;
    const float* fb = feat + (size_t)bn * C_ * HW_ + hw0;

    #pragma unroll 8
    for (int c = 0; c < C_; ++c) {
        float2 rw = *(const float2*)(fb + (size_t)c * HW_);
        if (ht.x) unsafeAtomicAdd(s0 + c, rw.x);
        if (ht.y) unsafeAtomicAdd(s1 + c, rw.y);
    }
}

__global__ __launch_bounds__(256) void gemm_atomic_kernel(
    const float* __restrict__ sums,
    const unsigned* __restrict__ cnts,
    const float* __restrict__ conf,
    const float* __restrict__ wfc,
    const float* __restrict__ bfc,
    float* __restrict__ outp)
{
    const int VPB = 32;
    __shared__ float wl[65][128];
    __shared__ float voxT[65][36];
    __shared__ float bl[128];
    __shared__ float invc[VPB];
    int tid = threadIdx.x;
    int bv0 = blockIdx.x * VPB;

    for (int i = tid; i < 65 * 128; i += 256)
        wl[i >> 7][i & 127] = wfc[i];
    if (tid < 128) bl[tid] = bfc[tid];
    if (tid < VPB) {
        unsigned cn = cnts[bv0 + tid];
        invc[tid] = 1.0f / (float)(cn > 1u ? cn : 1u);
        voxT[64][tid] = conf[bv0 + tid];
    }
    __syncthreads();

    for (int i = tid; i < VPB * C_; i += 256) {
        int vx = i >> 6, c = i & 63;
        voxT[c][vx] = sums[(size_t)bv0 * C_ + i] * invc[vx];
    }
    __syncthreads();

    int oc = tid & 31;
    int vr = tid >> 5;
    float acc[4][4];
    float4 bq = *(float4*)&bl[oc * 4];
    #pragma unroll
    for (int i = 0; i < 4; ++i) {
        acc[i][0] = bq.x; acc[i][1] = bq.y; acc[i][2] = bq.z; acc[i][3] = bq.w;
    }

    #pragma unroll
    for (int c = 0; c < 65; ++c) {
        float4 v4 = *(float4*)&voxT[c][vr * 4];
        float4 w4 = *(float4*)&wl[c][oc * 4];
        acc[0][0] += v4.x * w4.x; acc[0][1] += v4.x * w4.y; acc[0][2] += v4.x * w4.z; acc[0][3] += v4.x * w4.w;
        acc[1][0] += v4.y * w4.x; acc[1][1] += v4.y * w4.y; acc[1][2] += v4.y * w4.z; acc[1][3] += v4.y * w4.w;
        acc[2][0] += v4.z * w4.x; acc[2][1] += v4.z * w4.y; acc[2][2] += v4.z * w4.z; acc[2][3] += v4.z * w4.w;
        acc[3][0] += v4.w * w4.x; acc[3][1] += v4.w * w4.y; acc[3][2] += v4.w * w4.z; acc[3][3] += v4.w * w4.w;
    }

    #pragma unroll
    for (int i = 0; i < 4; ++i) {
        size_t bv = (size_t)(bv0 + vr * 4 + i);
        float4 st;
        st.x = acc[i][0]; st.y = acc[i][1]; st.z = acc[i][2]; st.w = acc[i][3];
        *(float4*)&outp[bv * OUT_ + oc * 4] = st;
    }
}

extern "C" void kernel_launch(void* const* d_in, const int* in_sizes, int n_in,
                              void* d_out, int out_size, void* d_ws, size_t ws_size,
                              hipStream_t stream) {
    const float* pose = (const float*)d_in[0];
    const float* intr = (const float*)d_in[1];
    const float* feat = (const float*)d_in[2];
    // d_in[3] = depths (unused by reference)
    const float* conf = (const float*)d_in[4];
    const int* vox_ids = (const int*)d_in[5];
    const int* hit = (const int*)d_in[6];
    const float* wfc = (const float*)d_in[7];
    const float* bfc = (const float*)d_in[8];

    float* out = (float*)d_out;
    float* dray = out + (size_t)B_ * V_ * OUT_;  // d follows out

    ray_kernel<<<(B_ * N_ * HW_) / 256, 256, 0, stream>>>(pose, intr, dray);

    size_t means_bytes = (size_t)B_ * V_ * C_ * sizeof(float);   // 102.4 MB
    size_t hist_bytes  = (size_t)BV_ * sizeof(unsigned);         // 1.6 MB
    // layout: means | hist | offsets | blockSums(256) | blockOffsets(256) | sortedIdx
    size_t need = means_bytes + 2 * hist_bytes + 512 * sizeof(unsigned)
                + (size_t)BR_ * sizeof(unsigned);                // ~108.7 MB

    if (ws_size >= need) {
        // -------- count-sort + segmented gather path (no float atomics) --------
        float* means = (float*)d_ws;
        unsigned* hist = (unsigned*)((char*)d_ws + means_bytes);
        unsigned* offsets = hist + BV_;
        unsigned* blockSums = offsets + BV_;
        unsigned* blockOffsets = blockSums + 256;
        unsigned* sortedIdx = blockOffsets + 256;

        hipMemsetAsync(hist, 0, hist_bytes, stream);
        hist_kernel<<<BR_ / 256, 256, 0, stream>>>(vox_ids, hit, hist);
        scanA_kernel<<<SCAN_BLOCKS, 256, 0, stream>>>(hist, blockSums);
        scanB_kernel<<<1, 256, 0, stream>>>(blockSums, blockOffsets);
        scanC_kernel<<<SCAN_BLOCKS, 256, 0, stream>>>(hist, blockOffsets, offsets);
        permute_kernel<<<BR_ / 256, 256, 0, stream>>>(vox_ids, hit, offsets, sortedIdx);
        gather_kernel<<<BV_ / 4, 256, 0, stream>>>(feat, hist, offsets, sortedIdx, means);
        gemm_mean_kernel<<<BV_ / 32, 256, 0, stream>>>(means, conf, wfc, bfc, out);
    } else {
        // -------- fallback: previous verified atomic path --------
        float* sums = (float*)d_ws;
        size_t sums_bytes = means_bytes;
        unsigned* cnts = (unsigned*)((char*)d_ws + sums_bytes);
        size_t cnts_bytes = (size_t)B_ * V_ * sizeof(unsigned);

        hipMemsetAsync(d_ws, 0, sums_bytes + cnts_bytes, stream);
        scatter_kernel<<<(B_ * N_ * HW_) / (256 * 2), 256, 0, stream>>>(feat, vox_ids, hit, sums, cnts);
        gemm_atomic_kernel<<<(B_ * V_) / 32, 256, 0, stream>>>(sums, cnts, conf, wfc, bfc, out);
    }
}

// Round 3
// 621.243 us; speedup vs baseline: 2.7032x; 1.4906x over previous
//
#include <hip/hip_runtime.h>
#include <hip/hip_bf16.h>

#define B_ 2
#define N_ 8
#define C_ 64
#define H_ 192
#define W_ 256
#define V_ 200000
#define OUT_ 128
#define HW_ (H_*W_)        // 49152
#define R_ (N_*HW_)        // 393216
#define BV_ (B_*V_)        // 400000
#define BR_ (B_*R_)        // 786432
#define SCAN_E 2048
#define SCAN_BLOCKS ((BV_ + SCAN_E - 1)/SCAN_E)   // 196

// ---------------- Kernel 1: ray directions ----------------
__global__ __launch_bounds__(256) void ray_kernel(
    const float* __restrict__ pose,
    const float* __restrict__ intr,
    float* __restrict__ dout)
{
    const int blocksPerBN = HW_ / 256;  // 192
    int tid = threadIdx.x;
    int bn = blockIdx.x / blocksPerBN;
    int hw = (blockIdx.x % blocksPerBN) * 256 + tid;
    int h = hw / W_, w = hw % W_;

    __shared__ float p[12];
    __shared__ float it[4];
    if (tid < 12) p[tid] = pose[bn * 16 + tid];
    if (tid >= 12 && tid < 16) it[tid - 12] = intr[bn * 6 + (tid - 12)];
    __syncthreads();

    float fx = it[0], fy = it[1], cx = it[2], cy = it[3];
    float uu = ((float)w - cx) / fx;
    float vv = ((float)h - cy) / fy;
    float dx = p[0] * uu + p[1] * vv + p[2];
    float dy = p[4] * uu + p[5] * vv + p[6];
    float dz = p[8] * uu + p[9] * vv + p[10];
    float inv = rsqrtf(dx * dx + dy * dy + dz * dz);
    size_t o = (size_t)(bn * HW_ + hw) * 3;
    dout[o + 0] = dx * inv;
    dout[o + 1] = dy * inv;
    dout[o + 2] = dz * inv;
}

// ---------------- histogram over voxel keys ----------------
__global__ __launch_bounds__(256) void hist_kernel(
    const int* __restrict__ vox,
    const int* __restrict__ hit,
    unsigned* __restrict__ hist)
{
    int t = blockIdx.x * 256 + threadIdx.x;   // 0 .. BR_-1
    if (t >= BR_) return;
    int b = t / R_;
    if (hit[t]) atomicAdd(&hist[b * V_ + vox[t]], 1u);
}

// ---------------- 3-phase exclusive scan over hist[BV_] -> offsets ----------------
__global__ __launch_bounds__(256) void scanA_kernel(
    const unsigned* __restrict__ hist,
    unsigned* __restrict__ blockSums)
{
    int tid = threadIdx.x;
    int base = blockIdx.x * SCAN_E + tid * 8;
    unsigned s = 0;
    #pragma unroll
    for (int j = 0; j < 8; ++j) {
        int idx = base + j;
        if (idx < BV_) s += hist[idx];
    }
    __shared__ unsigned sh[256];
    sh[tid] = s; __syncthreads();
    for (int d = 128; d > 0; d >>= 1) {
        if (tid < d) sh[tid] += sh[tid + d];
        __syncthreads();
    }
    if (tid == 0) blockSums[blockIdx.x] = sh[0];
}

__global__ __launch_bounds__(256) void scanB_kernel(
    const unsigned* __restrict__ blockSums,
    unsigned* __restrict__ blockOffsets)
{
    int tid = threadIdx.x;
    unsigned v = (tid < SCAN_BLOCKS) ? blockSums[tid] : 0u;
    __shared__ unsigned sh[256];
    sh[tid] = v; __syncthreads();
    for (int d = 1; d < 256; d <<= 1) {
        unsigned t = (tid >= d) ? sh[tid - d] : 0u;
        __syncthreads();
        sh[tid] += t;
        __syncthreads();
    }
    if (tid < SCAN_BLOCKS) blockOffsets[tid] = sh[tid] - v;   // exclusive
}

__global__ __launch_bounds__(256) void scanC_kernel(
    const unsigned* __restrict__ hist,
    const unsigned* __restrict__ blockOffsets,
    unsigned* __restrict__ offsets)
{
    int tid = threadIdx.x;
    int base = blockIdx.x * SCAN_E + tid * 8;
    unsigned e[8];
    unsigned s = 0;
    #pragma unroll
    for (int j = 0; j < 8; ++j) {
        int idx = base + j;
        e[j] = (idx < BV_) ? hist[idx] : 0u;
        s += e[j];
    }
    __shared__ unsigned sh[256];
    sh[tid] = s; __syncthreads();
    for (int d = 1; d < 256; d <<= 1) {
        unsigned t = (tid >= d) ? sh[tid - d] : 0u;
        __syncthreads();
        sh[tid] += t;
        __syncthreads();
    }
    unsigned run = blockOffsets[blockIdx.x] + (sh[tid] - s);
    #pragma unroll
    for (int j = 0; j < 8; ++j) {
        int idx = base + j;
        if (idx < BV_) offsets[idx] = run;
        run += e[j];
    }
}

// ---------------- scatter features into sorted order ----------------
// Thread = pixel. Streaming coalesced reads of feat; dense 256B record write
// to gathered[slot]. Slot via atomic ticket on offs2 (scratch copy of offsets).
// Covers batches b0 .. b0+nb-1; gathered indexed relative to offsets[b0*V].
__global__ __launch_bounds__(256) void scatterfeat_kernel(
    const float* __restrict__ feat,
    const int* __restrict__ vox,
    const int* __restrict__ hit,
    const unsigned* __restrict__ offsets,
    unsigned* __restrict__ offs2,
    float* __restrict__ gathered,
    int b0)
{
    int t = blockIdx.x * 256 + threadIdx.x;
    int p = b0 * R_ + t;                       // global pixel index
    if (!hit[p]) return;
    int b = p / R_;
    int r = p - b * R_;
    unsigned base = offsets[(size_t)b0 * V_];
    int key = b * V_ + vox[p];
    unsigned pos = atomicAdd(&offs2[key], 1u) - base;

    int n = r / HW_;
    int hw = r - n * HW_;
    const float* fb = feat + ((size_t)b * N_ + n) * (size_t)(C_ * HW_) + hw;

    float v[64];
    #pragma unroll
    for (int c = 0; c < 64; ++c) v[c] = fb[(size_t)c * HW_];

    float4* gp = (float4*)(gathered + (size_t)pos * 64);
    #pragma unroll
    for (int q = 0; q < 16; ++q) {
        float4 st; st.x = v[4*q]; st.y = v[4*q+1]; st.z = v[4*q+2]; st.w = v[4*q+3];
        gp[q] = st;
    }
}

// ---------------- fused segment-mean + concat(conf) + GEMM + bias ----------------
// Block = 32 voxels (contiguous span of gathered). 4 waves x 8 voxels each,
// lanes = channels, coalesced segment reads. Then the register-tile GEMM.
__global__ __launch_bounds__(256) void gemm_fused_kernel(
    const float* __restrict__ gathered,
    const unsigned* __restrict__ hist,
    const unsigned* __restrict__ offsets,
    const float* __restrict__ conf,
    const float* __restrict__ wfc,
    const float* __restrict__ bfc,
    float* __restrict__ outp,
    int b0)
{
    const int VPB = 32;
    __shared__ float wl[65][128];
    __shared__ float voxT[65][36];
    __shared__ float bl[128];
    int tid = threadIdx.x;
    int bv0 = b0 * V_ + blockIdx.x * VPB;
    unsigned base = offsets[(size_t)b0 * V_];

    for (int i = tid; i < 65 * 128; i += 256)
        wl[i >> 7][i & 127] = wfc[i];
    if (tid < 128) bl[tid] = bfc[tid];
    if (tid < VPB) voxT[64][tid] = conf[bv0 + tid];

    // segment means
    int lane = tid & 63;
    int wv = tid >> 6;
    #pragma unroll
    for (int i = 0; i < 8; ++i) {
        int lv = wv * 8 + i;
        int bv = bv0 + lv;
        unsigned cnt = hist[bv];
        unsigned st = offsets[bv] - base;
        float acc = 0.0f;
        for (unsigned k = 0; k < cnt; ++k)
            acc += gathered[(size_t)(st + k) * 64 + lane];
        voxT[lane][lv] = acc / fmaxf((float)cnt, 1.0f);
    }
    __syncthreads();

    int oc = tid & 31;
    int vr = tid >> 5;
    float acc[4][4];
    float4 bq = *(float4*)&bl[oc * 4];
    #pragma unroll
    for (int i = 0; i < 4; ++i) {
        acc[i][0] = bq.x; acc[i][1] = bq.y; acc[i][2] = bq.z; acc[i][3] = bq.w;
    }

    #pragma unroll
    for (int c = 0; c < 65; ++c) {
        float4 v4 = *(float4*)&voxT[c][vr * 4];
        float4 w4 = *(float4*)&wl[c][oc * 4];
        acc[0][0] += v4.x * w4.x; acc[0][1] += v4.x * w4.y; acc[0][2] += v4.x * w4.z; acc[0][3] += v4.x * w4.w;
        acc[1][0] += v4.y * w4.x; acc[1][1] += v4.y * w4.y; acc[1][2] += v4.y * w4.z; acc[1][3] += v4.y * w4.w;
        acc[2][0] += v4.z * w4.x; acc[2][1] += v4.z * w4.y; acc[2][2] += v4.z * w4.z; acc[2][3] += v4.z * w4.w;
        acc[3][0] += v4.w * w4.x; acc[3][1] += v4.w * w4.y; acc[3][2] += v4.w * w4.z; acc[3][3] += v4.w * w4.w;
    }

    #pragma unroll
    for (int i = 0; i < 4; ++i) {
        size_t bv = (size_t)(bv0 + vr * 4 + i);
        float4 st;
        st.x = acc[i][0]; st.y = acc[i][1]; st.z = acc[i][2]; st.w = acc[i][3];
        *(float4*)&outp[bv * OUT_ + oc * 4] = st;
    }
}

// ---------------- Fallback atomic path (verified previously) ----------------
__global__ __launch_bounds__(256) void scatter_kernel(
    const float* __restrict__ feat,
    const int* __restrict__ vox_ids,
    const int* __restrict__ hit,
    float* __restrict__ sums,
    unsigned* __restrict__ cnts)
{
    const int PPT = 2;
    const int blocksPerBN = HW_ / (256 * PPT);  // 96
    int tid = threadIdx.x;
    int bn = blockIdx.x / blocksPerBN;
    int b = bn >> 3;
    int hw0 = (blockIdx.x % blocksPerBN) * (256 * PPT) + tid * PPT;
    int r0 = (bn & 7) * HW_ + hw0;

    int2 vid = *(const int2*)(vox_ids + (size_t)b * R_ + r0);
    int2 ht  = *(const int2*)(hit + (size_t)b * R_ + r0);
    if (!(ht.x | ht.y)) return;

    unsigned* cb = cnts + (size_t)b * V_;
    if (ht.x) atomicAdd(&cb[vid.x], 1u);
    if (ht.y) atomicAdd(&cb[vid.y], 1u);

    float* sb = sums + (size_t)b * (size_t)V_ * C_;
    float* s0 = sb + (size_t)vid.x * C_;
    float* s1 = sb + (size_t)vid.y * C_;
    const float* fb = feat + (size_t)bn * C_ * HW_ + hw0;

    #pragma unroll 8
    for (int c = 0; c < C_; ++c) {
        float2 rw = *(const float2*)(fb + (size_t)c * HW_);
        if (ht.x) unsafeAtomicAdd(s0 + c, rw.x);
        if (ht.y) unsafeAtomicAdd(s1 + c, rw.y);
    }
}

__global__ __launch_bounds__(256) void gemm_atomic_kernel(
    const float* __restrict__ sums,
    const unsigned* __restrict__ cnts,
    const float* __restrict__ conf,
    const float* __restrict__ wfc,
    const float* __restrict__ bfc,
    float* __restrict__ outp)
{
    const int VPB = 32;
    __shared__ float wl[65][128];
    __shared__ float voxT[65][36];
    __shared__ float bl[128];
    __shared__ float invc[VPB];
    int tid = threadIdx.x;
    int bv0 = blockIdx.x * VPB;

    for (int i = tid; i < 65 * 128; i += 256)
        wl[i >> 7][i & 127] = wfc[i];
    if (tid < 128) bl[tid] = bfc[tid];
    if (tid < VPB) {
        unsigned cn = cnts[bv0 + tid];
        invc[tid] = 1.0f / (float)(cn > 1u ? cn : 1u);
        voxT[64][tid] = conf[bv0 + tid];
    }
    __syncthreads();

    for (int i = tid; i < VPB * C_; i += 256) {
        int vx = i >> 6, c = i & 63;
        voxT[c][vx] = sums[(size_t)bv0 * C_ + i] * invc[vx];
    }
    __syncthreads();

    int oc = tid & 31;
    int vr = tid >> 5;
    float acc[4][4];
    float4 bq = *(float4*)&bl[oc * 4];
    #pragma unroll
    for (int i = 0; i < 4; ++i) {
        acc[i][0] = bq.x; acc[i][1] = bq.y; acc[i][2] = bq.z; acc[i][3] = bq.w;
    }

    #pragma unroll
    for (int c = 0; c < 65; ++c) {
        float4 v4 = *(float4*)&voxT[c][vr * 4];
        float4 w4 = *(float4*)&wl[c][oc * 4];
        acc[0][0] += v4.x * w4.x; acc[0][1] += v4.x * w4.y; acc[0][2] += v4.x * w4.z; acc[0][3] += v4.x * w4.w;
        acc[1][0] += v4.y * w4.x; acc[1][1] += v4.y * w4.y; acc[1][2] += v4.y * w4.z; acc[1][3] += v4.y * w4.w;
        acc[2][0] += v4.z * w4.x; acc[2][1] += v4.z * w4.y; acc[2][2] += v4.z * w4.z; acc[2][3] += v4.z * w4.w;
        acc[3][0] += v4.w * w4.x; acc[3][1] += v4.w * w4.y; acc[3][2] += v4.w * w4.z; acc[3][3] += v4.w * w4.w;
    }

    #pragma unroll
    for (int i = 0; i < 4; ++i) {
        size_t bv = (size_t)(bv0 + vr * 4 + i);
        float4 st;
        st.x = acc[i][0]; st.y = acc[i][1]; st.z = acc[i][2]; st.w = acc[i][3];
        *(float4*)&outp[bv * OUT_ + oc * 4] = st;
    }
}

extern "C" void kernel_launch(void* const* d_in, const int* in_sizes, int n_in,
                              void* d_out, int out_size, void* d_ws, size_t ws_size,
                              hipStream_t stream) {
    const float* pose = (const float*)d_in[0];
    const float* intr = (const float*)d_in[1];
    const float* feat = (const float*)d_in[2];
    // d_in[3] = depths (unused by reference)
    const float* conf = (const float*)d_in[4];
    const int* vox_ids = (const int*)d_in[5];
    const int* hit = (const int*)d_in[6];
    const float* wfc = (const float*)d_in[7];
    const float* bfc = (const float*)d_in[8];

    float* out = (float*)d_out;
    float* dray = out + (size_t)B_ * V_ * OUT_;  // d follows out

    ray_kernel<<<(B_ * N_ * HW_) / 256, 256, 0, stream>>>(pose, intr, dray);

    size_t hist_bytes = (size_t)BV_ * sizeof(unsigned);                 // 1.6 MB
    size_t gath_full  = (size_t)BR_ * C_ * sizeof(float);               // 201.3 MB
    size_t gath_batch = (size_t)R_ * C_ * sizeof(float);                // 100.7 MB
    size_t ovh = 3 * hist_bytes + 512 * sizeof(unsigned);               // hist+offsets+offs2+scan tmp
    size_t need_full  = gath_full + ovh;                                // ~206.1 MB
    size_t need_batch = gath_batch + ovh;                               // ~105.5 MB

    if (ws_size >= need_batch) {
        size_t gath_bytes = (ws_size >= need_full) ? gath_full : gath_batch;
        float* gathered = (float*)d_ws;
        unsigned* hist = (unsigned*)((char*)d_ws + gath_bytes);
        unsigned* offsets = hist + BV_;
        unsigned* offs2 = offsets + BV_;
        unsigned* blockSums = offs2 + BV_;
        unsigned* blockOffsets = blockSums + 256;

        hipMemsetAsync(hist, 0, hist_bytes, stream);
        hist_kernel<<<BR_ / 256, 256, 0, stream>>>(vox_ids, hit, hist);
        scanA_kernel<<<SCAN_BLOCKS, 256, 0, stream>>>(hist, blockSums);
        scanB_kernel<<<1, 256, 0, stream>>>(blockSums, blockOffsets);
        scanC_kernel<<<SCAN_BLOCKS, 256, 0, stream>>>(hist, blockOffsets, offsets);
        hipMemcpyAsync(offs2, offsets, hist_bytes, hipMemcpyDeviceToDevice, stream);

        if (ws_size >= need_full) {
            // single pass over both batches
            scatterfeat_kernel<<<BR_ / 256, 256, 0, stream>>>(feat, vox_ids, hit, offsets, offs2, gathered, 0);
            gemm_fused_kernel<<<BV_ / 32, 256, 0, stream>>>(gathered, hist, offsets, conf, wfc, bfc, out, 0);
        } else {
            // per-batch passes sharing one gathered buffer (stream-serialized)
            for (int b = 0; b < B_; ++b) {
                scatterfeat_kernel<<<R_ / 256, 256, 0, stream>>>(feat, vox_ids, hit, offsets, offs2, gathered, b);
                gemm_fused_kernel<<<V_ / 32, 256, 0, stream>>>(gathered, hist, offsets, conf, wfc, bfc, out, b);
            }
        }
    } else {
        // -------- fallback: verified atomic path --------
        float* sums = (float*)d_ws;
        size_t sums_bytes = (size_t)B_ * V_ * C_ * sizeof(float);
        unsigned* cnts = (unsigned*)((char*)d_ws + sums_bytes);
        size_t cnts_bytes = (size_t)B_ * V_ * sizeof(unsigned);

        hipMemsetAsync(d_ws, 0, sums_bytes + cnts_bytes, stream);
        scatter_kernel<<<(B_ * N_ * HW_) / (256 * 2), 256, 0, stream>>>(feat, vox_ids, hit, sums, cnts);
        gemm_atomic_kernel<<<(B_ * V_) / 32, 256, 0, stream>>>(sums, cnts, conf, wfc, bfc, out);
    }
}